// Round 6
// baseline (400.780 us; speedup 1.0000x reference)
//
#include <hip/hip_runtime.h>
#include <math.h>

// Problem constants (fixed by setup_inputs)
#define NB 2
#define NH 12
#define NW 12
#define NK 3
#define NI 32
#define NO 32
#define NBHW (NB*NH*NW)        // 288 spatial positions
#define NC (NK*NK*NI)          // 288 children per position
#define VPB (NC*NO*16)         // 147456 votes floats per bhw (o-major, a-minor)
#define HR 14
#define WR 14
#define EPSF 1e-7f
#define MINVAR 5e-4f
#define TEMP0 0.0005f          // 0.01*(1-0.95^1), m_step it=0
#define TEMPF 0.00142625f      // 0.01*(1-0.95^3), final m_step

// CH=4 proven best. Votes-pass rate is invariant to occupancy/ILP (R3/R4);
// launch count and non-hidden cross-kernel traffic are the only live levers
// (R5: +2 launches with -45MB redundant work = +4us).
#define CH 4
#define CPC (NC/CH)            // 72 children per chunk
#define NBLK (NBHW*CH)         // 1152 chunk-blocks
#define ITERS (CPC/2)          // 36 iters, 2 children per block-iteration

// ---- Workspace layout (float offsets) ----
// CNT: [288] kA finalize counters + [288] kD finalize counters (memset to 0).
#define CNT_N 576
#define DENSE_N (NB*HR*WR*NI)  // 12544
#define DENSE_OFF CNT_N
#define S1_OFF    (DENSE_OFF + DENSE_N)      // [NBLK][512] chunk partials
#define S2_OFF    (S1_OFF + NBLK*512)
#define SR_OFF    (S2_OFF + NBLK*512)        // [NBLK]
#define MU_OFF    (SR_OFF + NBLK)            // [288][512] stored (a*32+o)
#define W_OFF     (MU_OFF + NBHW*512)        // 0.5/sig, same layout
#define L_OFF     (W_OFF + NBHW*512)         // [288][32]
#define BM_OFF    (L_OFF + NBHW*32)          // [NBLK] per-block lognum max
#define M_OFF     (BM_OFF + NBLK)            // [4] global lognum max (from kC)
#define LOG_OFF   (M_OFF + 4)                // [288][288][32] lognum
#define DSR_OFF   (LOG_OFF + NBHW*NC*NO)     // [NBLK][32] per-o sumR (kD)
// kD reuses S1/S2 (kA's finalize consumed them before kD runs).

// ================= kA: m_step 1 partial moments + last-block finalize ======
// grid = NBLK, block = 256. Also zeroes the dense grid (consumed by kC/kD).
// The last chunk-block per bhw (atomic counter) computes mu/sig/L once.
// Protocol (correctness-proven in R1/R2 on this chip): RELEASE fetch_add
// publishes this block's slot writes (wbl2); the winning block does ONE
// ACQUIRE fence (buffer_inv) before reading the other chunks' slots.
__global__ __launch_bounds__(256) void kA(const float* __restrict__ votes,
        const float* __restrict__ acts, const float* __restrict__ beta_a,
        const float* __restrict__ beta_u, float* __restrict__ ws) {
    __shared__ float s_acts[CPC];
    __shared__ float4 r1[128], r2[128];
    __shared__ float sR1;
    __shared__ int lastf;
    const int bid = blockIdx.x;
    const int bhw = bid >> 2;
    const int cbase = (bid & 3) * CPC;
    const int t = threadIdx.x;
    {   // fold dense-grid zeroing into the first kernel
        const int idx = bid*256 + t;
        if (idx < DENSE_N) ws[DENSE_OFF + idx] = 0.f;
    }
    if (t < CPC) s_acts[t] = acts[bhw*NC + cbase + t] * (1.0f/NO);
    __syncthreads();
    const int child_sub = t >> 7;
    const int rem = t & 127;
    const float4* vb4 = (const float4*)votes + (size_t)bhw*(VPB/4);
    float s1[4] = {0,0,0,0}, s2[4] = {0,0,0,0};
    float sumR = 0.f;
    #pragma unroll 6
    for (int it = 0; it < ITERS; ++it) {
        const int c_loc = it*2 + child_sub;
        float4 v = vb4[(size_t)(cbase + c_loc)*128 + rem];
        float ra = s_acts[c_loc];
        s1[0] += ra*v.x; s2[0] = fmaf(ra*v.x, v.x, s2[0]);
        s1[1] += ra*v.y; s2[1] = fmaf(ra*v.y, v.y, s2[1]);
        s1[2] += ra*v.z; s2[2] = fmaf(ra*v.z, v.z, s2[2]);
        s1[3] += ra*v.w; s2[3] = fmaf(ra*v.w, v.w, s2[3]);
        sumR += ra;
    }
    if (child_sub) {
        r1[rem] = make_float4(s1[0], s1[1], s1[2], s1[3]);
        r2[rem] = make_float4(s2[0], s2[1], s2[2], s2[3]);
        if (rem == 0) sR1 = sumR;
    }
    __syncthreads();
    if (!child_sub) {
        float4 o1 = r1[rem], o2 = r2[rem];
        ((float4*)(ws + S1_OFF))[bid*128 + rem] =
            make_float4(s1[0]+o1.x, s1[1]+o1.y, s1[2]+o1.z, s1[3]+o1.w);
        ((float4*)(ws + S2_OFF))[bid*128 + rem] =
            make_float4(s2[0]+o2.x, s2[1]+o2.y, s2[2]+o2.z, s2[3]+o2.w);
        if (rem == 0) ws[SR_OFF + bid] = sumR + sR1;
    }
    // ---- last-block-per-bhw finalize (replaces the kB0 launch) ----
    __syncthreads();   // compiler emits vmcnt(0) before s_barrier: stores retired
    if (t == 0) {
        unsigned prev = __hip_atomic_fetch_add((unsigned*)ws + bhw, 1u,
                            __ATOMIC_RELEASE, __HIP_MEMORY_SCOPE_AGENT);
        lastf = (prev == CH - 1);
        if (lastf) __builtin_amdgcn_fence(__ATOMIC_ACQUIRE, "agent");
    }
    __syncthreads();
    if (lastf) {
        float sR = 0.f;
        #pragma unroll
        for (int s = 0; s < CH; ++s) sR += ws[SR_OFF + bhw*CH + s];
        #pragma unroll
        for (int half = 0; half < 2; ++half) {
            const int idx = t + half*256;        // = o*16 + a
            float a1 = 0.f, a2 = 0.f;
            #pragma unroll
            for (int s = 0; s < CH; ++s) {
                a1 += ws[S1_OFF + (size_t)(bhw*CH + s)*512 + idx];
                a2 += ws[S2_OFF + (size_t)(bhw*CH + s)*512 + idx];
            }
            const int o = idx >> 4, a = idx & 15;
            float mu  = a1 / (sR + EPSF);
            float sig = (a2 - mu*(2.f*a1 - mu*sR)) / (sR + EPSF) + MINVAR;
            ws[MU_OFF + bhw*512 + a*32 + o] = mu;
            ws[W_OFF  + bhw*512 + a*32 + o] = 0.5f / sig;
            float cost = (beta_u[o] - 0.5f*logf(sig + EPSF)) * sR;
            float ps   = logf(6.2831853071795864f * sig);
            #pragma unroll
            for (int d = 1; d < 16; d <<= 1) {
                cost += __shfl_xor(cost, d);
                ps   += __shfl_xor(ps, d);
            }
            if (a == 0) {
                float aj = 1.0f/(1.0f + expf(-TEMP0*(beta_a[o] - cost)));
                ws[L_OFF + bhw*32 + o] = logf(aj) - ps;
            }
        }
    }
}

// ================= kB: lognum pass over votes (lean) ========================
// grid = NBLK, block = 256. Loads mu/w/L computed once by kA's finalize.
__global__ __launch_bounds__(256) void kB(const float* __restrict__ votes,
        float* __restrict__ ws) {
    __shared__ float s_mu[512], s_w[512], s_L[32], smax[4];
    const int bid = blockIdx.x;
    const int bhw = bid >> 2;
    const int cbase = (bid & 3) * CPC;
    const int t = threadIdx.x;
    s_mu[t]     = ws[MU_OFF + bhw*512 + t];
    s_mu[t+256] = ws[MU_OFF + bhw*512 + t + 256];
    s_w[t]      = ws[W_OFF + bhw*512 + t];
    s_w[t+256]  = ws[W_OFF + bhw*512 + t + 256];
    if (t < 32) s_L[t] = ws[L_OFF + bhw*32 + t];
    __syncthreads();
    const int child_sub = t >> 7;
    const int rem = t & 127;
    const int o = rem >> 2;
    const int quad = rem & 3;
    float mur[4], wr[4];
    #pragma unroll
    for (int j = 0; j < 4; ++j) {
        mur[j] = s_mu[(quad*4 + j)*32 + o];
        wr[j]  = s_w [(quad*4 + j)*32 + o];
    }
    const float L = s_L[o];
    const float4* vb4 = (const float4*)votes + (size_t)bhw*(VPB/4);
    float* lp = ws + LOG_OFF + (size_t)bhw*(NC*NO);
    float tmax = -3.0e38f;
    #pragma unroll 6
    for (int it = 0; it < ITERS; ++it) {
        const int c = cbase + it*2 + child_sub;
        float4 v = vb4[(size_t)c*128 + rem];
        float d0 = v.x - mur[0];
        float acc = d0*d0*wr[0];
        float d1 = v.y - mur[1]; acc = fmaf(d1*d1, wr[1], acc);
        float d2 = v.z - mur[2]; acc = fmaf(d2*d2, wr[2], acc);
        float d3 = v.w - mur[3]; acc = fmaf(d3*d3, wr[3], acc);
        acc += __shfl_xor(acc, 1);
        acc += __shfl_xor(acc, 2);          // all quads hold the full a-sum
        float ln = L - acc;
        if (quad == 0) lp[c*32 + o] = ln;
        tmax = fmaxf(tmax, ln);
    }
    #pragma unroll
    for (int d = 1; d < 64; d <<= 1) tmax = fmaxf(tmax, __shfl_xor(tmax, d));
    if ((t & 63) == 0) smax[t >> 6] = tmax;
    __syncthreads();
    if (t == 0)
        ws[BM_OFF + bid] = fmaxf(fmaxf(smax[0], smax[1]), fmaxf(smax[2], smax[3]));
}

// ================= kC: inline global max + exp/sum_o + scatter =============
// grid = NBLK, block = 256; t -> (c_loc = t>>5, o = t&31). Publishes M.
__global__ __launch_bounds__(256) void kC(float* __restrict__ ws) {
    __shared__ float smax[4];
    const int bid = blockIdx.x;
    const int bhw = bid >> 2;
    const int cbase = (bid & 3) * CPC;
    const int t = threadIdx.x;
    float m = -3.0e38f;
    for (int i = t; i < NBLK; i += 256) m = fmaxf(m, ws[BM_OFF + i]);
    #pragma unroll
    for (int d = 1; d < 64; d <<= 1) m = fmaxf(m, __shfl_xor(m, d));
    if ((t & 63) == 0) smax[t >> 6] = m;
    __syncthreads();
    const float M = fmaxf(fmaxf(smax[0], smax[1]), fmaxf(smax[2], smax[3]));
    if (bid == 0 && t == 0) ws[M_OFF] = M;   // for kD (kernel-boundary visible)
    const int b = bhw / (NH*NW);
    const int rem = bhw % (NH*NW);
    const int y = rem / NW, x = rem % NW;
    const float* lp = ws + LOG_OFF + (size_t)bhw*(NC*NO);
    float* dense = ws + DENSE_OFF;
    const int o = t & 31;
    for (int it = 0; it < CPC/8; ++it) {
        const int c = cbase + it*8 + (t >> 5);
        float s = expf(lp[c*32 + o] - M);
        #pragma unroll
        for (int d = 1; d < 32; d <<= 1) s += __shfl_xor(s, d);
        if (o == 0) {
            const int i = c & 31, kk = c >> 5;
            const int ky = kk / 3, kx = kk % 3;
            atomicAdd(&dense[((b*HR + y+ky)*WR + (x+kx))*NI + i], s);
        }
    }
}

// ================= kD: final m_step moments + last-block output ============
// grid = NBLK, block = 256. Last chunk-block per bhw writes the outputs
// (replaces the kD2 launch).
__global__ __launch_bounds__(256) void kD(const float* __restrict__ votes,
        const float* __restrict__ acts, const float* __restrict__ beta_a,
        const float* __restrict__ beta_u, float* __restrict__ ws,
        float* __restrict__ out) {
    __shared__ float s_rd[CPC];
    __shared__ float s_ra[CPC*NO];
    __shared__ float4 r1[128], r2[128];
    __shared__ float sSR[64];
    __shared__ int lastf;
    const int bid = blockIdx.x;
    const int bhw = bid >> 2;
    const int cbase = (bid & 3) * CPC;
    const int t = threadIdx.x;
    const int b = bhw / (NH*NW);
    const int remhw = bhw % (NH*NW);
    const int y = remhw / NW, x = remhw % NW;
    const float M = ws[M_OFF];
    if (t < CPC) {
        const int c = cbase + t;
        const int i = c & 31, kk = c >> 5;
        const int ky = kk / 3, kx = kk % 3;
        float dn = ws[DENSE_OFF + ((b*HR + y+ky)*WR + (x+kx))*NI + i];
        s_rd[t] = acts[bhw*NC + c] / (dn + EPSF);
    }
    __syncthreads();
    const float* lp = ws + LOG_OFF + (size_t)bhw*(NC*NO) + (size_t)cbase*32;
    for (int idx = t; idx < CPC*NO; idx += 256)
        s_ra[idx] = s_rd[idx >> 5] * expf(lp[idx] - M);
    __syncthreads();
    const int child_sub = t >> 7;
    const int rem = t & 127;
    const int o = rem >> 2;
    const int quad = rem & 3;
    const float4* vb4 = (const float4*)votes + (size_t)bhw*(VPB/4);
    float s1[4] = {0,0,0,0}, s2[4] = {0,0,0,0};
    float sumR = 0.f;
    #pragma unroll 6
    for (int it = 0; it < ITERS; ++it) {
        const int c_loc = it*2 + child_sub;
        float4 v = vb4[(size_t)(cbase + c_loc)*128 + rem];
        float ra = s_ra[c_loc*32 + o];          // 4-lane broadcast
        s1[0] += ra*v.x; s2[0] = fmaf(ra*v.x, v.x, s2[0]);
        s1[1] += ra*v.y; s2[1] = fmaf(ra*v.y, v.y, s2[1]);
        s1[2] += ra*v.z; s2[2] = fmaf(ra*v.z, v.z, s2[2]);
        s1[3] += ra*v.w; s2[3] = fmaf(ra*v.w, v.w, s2[3]);
        sumR += ra;
    }
    // per-(child_sub, o) partial: quads are identical, take quad 0's only
    if (quad == 0) sSR[child_sub*32 + o] = sumR;
    if (child_sub) {
        r1[rem] = make_float4(s1[0], s1[1], s1[2], s1[3]);
        r2[rem] = make_float4(s2[0], s2[1], s2[2], s2[3]);
    }
    __syncthreads();
    if (!child_sub) {
        float4 o1 = r1[rem], o2 = r2[rem];
        ((float4*)(ws + S1_OFF))[bid*128 + rem] =
            make_float4(s1[0]+o1.x, s1[1]+o1.y, s1[2]+o1.z, s1[3]+o1.w);
        ((float4*)(ws + S2_OFF))[bid*128 + rem] =
            make_float4(s2[0]+o2.x, s2[1]+o2.y, s2[2]+o2.z, s2[3]+o2.w);
    }
    if (t < 32) ws[DSR_OFF + bid*32 + t] = sSR[t] + sSR[32 + t];
    // ---- last-block-per-bhw output write (replaces the kD2 launch) ----
    __syncthreads();   // stores retired (vmcnt(0) before s_barrier)
    if (t == 0) {
        unsigned prev = __hip_atomic_fetch_add((unsigned*)ws + NBHW + bhw, 1u,
                            __ATOMIC_RELEASE, __HIP_MEMORY_SCOPE_AGENT);
        lastf = (prev == CH - 1);
        if (lastf) __builtin_amdgcn_fence(__ATOMIC_ACQUIRE, "agent");
    }
    __syncthreads();
    if (lastf) {
        #pragma unroll
        for (int half = 0; half < 2; ++half) {
            const int idx = t + half*256;        // = o*16 + a
            const int oo = idx >> 4, a = idx & 15;
            float a1 = 0.f, a2 = 0.f, sR = 0.f;
            #pragma unroll
            for (int ch = 0; ch < CH; ++ch) {
                a1 += ws[S1_OFF + (size_t)(bhw*CH + ch)*512 + idx];
                a2 += ws[S2_OFF + (size_t)(bhw*CH + ch)*512 + idx];
                sR += ws[DSR_OFF + (bhw*CH + ch)*32 + oo];
            }
            float mu  = a1 / (sR + EPSF);
            float sig = (a2 - mu*(2.f*a1 - mu*sR)) / (sR + EPSF) + MINVAR;
            out[bhw*512 + idx] = mu;             // poses (b,h,w,o,a,a)
            float cost = (beta_u[oo] - 0.5f*logf(sig + EPSF)) * sR;
            #pragma unroll
            for (int d = 1; d < 16; d <<= 1) cost += __shfl_xor(cost, d);
            if (a == 0) {
                float aj = 1.0f/(1.0f + expf(-TEMPF*(beta_a[oo] - cost)));
                out[NBHW*512 + bhw*32 + oo] = aj; // acts (b,h,w,o)
            }
        }
    }
}

extern "C" void kernel_launch(void* const* d_in, const int* in_sizes, int n_in,
                              void* d_out, int out_size, void* d_ws, size_t ws_size,
                              hipStream_t stream) {
    const float* votes  = (const float*)d_in[0];
    const float* acts   = (const float*)d_in[1];
    const float* beta_a = (const float*)d_in[2];
    const float* beta_u = (const float*)d_in[3];
    float* ws  = (float*)d_ws;
    float* out = (float*)d_out;

    // zero the finalize counters (tiny, graph-capturable)
    hipMemsetAsync(d_ws, 0, CNT_N*sizeof(float), stream);
    kA<<<NBLK, 256, 0, stream>>>(votes, acts, beta_a, beta_u, ws);
    kB<<<NBLK, 256, 0, stream>>>(votes, ws);
    kC<<<NBLK, 256, 0, stream>>>(ws);
    kD<<<NBLK, 256, 0, stream>>>(votes, acts, beta_a, beta_u, ws, out);
}

// Round 7
// 316.307 us; speedup vs baseline: 1.2671x; 1.2671x over previous
//
#include <hip/hip_runtime.h>
#include <math.h>

// Problem constants (fixed by setup_inputs)
#define NB 2
#define NH 12
#define NW 12
#define NK 3
#define NI 32
#define NO 32
#define NA 16                 // a*a = 16 pose elements
#define NBHW (NB*NH*NW)       // 288 spatial positions
#define NC (NK*NK*NI)         // 288 children per position
#define CSTR (NO*NA)          // 512 floats per child (o-major, a-minor)
#define VPB (NC*CSTR)         // 147456 votes floats per bhw
#define HR 14
#define WR 14
#define EPSF 1e-7f
#define MINVAR 5e-4f
#define TEMP0 0.0005f         // 0.01*(1-0.95^1), m_step it=0
#define TEMPF 0.00142625f     // 0.01*(1-0.95^3), final m_step

#define CH 4                  // chunks of the child dim for votes passes
#define CPC (NC/CH)           // 72 children per chunk
#define ITERS (CPC/2)         // 36 iterations, 2 children per block-iteration
#define NBLK (NBHW*CH)        // 1152 chunk-blocks

// fp16 shadow copy of votes, written by kA, read by kB/kD.
// Mechanism (R6 counters): votes passes are capped by per-CU outstanding
// cache-line requests (rate invariant to occupancy R3 and ILP R4; VALU 2.4%,
// HBM 9%). Halving bytes/requests is the only lever that moves that cap.
typedef __attribute__((ext_vector_type(4))) _Float16 half4;

// ---- Workspace layout (float offsets) ----
#define PA_S1 0                        // [bid][512] (o*16+a)
#define PA_S2 (PA_S1 + NBLK*512)
#define PA_SR (PA_S2 + NBLK*512)       // [bid]
#define PD_S1 (PA_SR + NBLK)
#define PD_S2 (PD_S1 + NBLK*512)
#define PD_SR (PD_S2 + NBLK*512)       // [bid][32] (per-o)
#define BM_OFF (PD_SR + NBLK*32)       // [bid] per-block lognum max
#define DENSE_OFF (BM_OFF + NBLK)      // [b][y'][x'][i]
#define DENSE_N (NB*HR*WR*NI)          // 12544
#define LOGNUM_OFF (DENSE_OFF + DENSE_N)  // [bhw][c][o]
#define VH_OFF (LOGNUM_OFF + NBHW*NC*NO)  // fp16 votes: [bhw][c][128] half4

// ---------------- Kernel A: m_step 1 partial moments (R uniform = 1/NO) ----
// grid = NBLK, block = 256. Also zeroes the dense grid (consumed by kC) and
// writes the fp16 shadow votes while the fp32 stream is in registers.
__global__ __launch_bounds__(256) void kA(const float* __restrict__ votes,
        const float* __restrict__ acts, float* __restrict__ ws) {
    __shared__ float s_acts[CPC];
    __shared__ float4 r1[128], r2[128];
    __shared__ float sR1;
    const int bid = blockIdx.x;
    const int bhw = bid >> 2;
    const int cbase = (bid & 3) * CPC;
    const int t = threadIdx.x;
    {   // fold dense-grid zeroing into the first kernel
        const int idx = bid*256 + t;
        if (idx < DENSE_N) ws[DENSE_OFF + idx] = 0.f;
    }
    if (t < CPC) s_acts[t] = acts[bhw*NC + cbase + t] * (1.0f/NO);
    __syncthreads();
    const int child_sub = t >> 7;
    const int rem = t & 127;
    const float4* vb4 = (const float4*)votes + (size_t)bhw*(VPB/4);
    half4* vh4 = (half4*)(ws + VH_OFF) + (size_t)bhw*(VPB/4);
    float s1[4] = {0,0,0,0}, s2[4] = {0,0,0,0};
    float sumR = 0.f;
    #pragma unroll 6
    for (int it = 0; it < ITERS; ++it) {
        const int c_loc = it*2 + child_sub;
        float4 v = vb4[(size_t)(cbase + c_loc)*128 + rem];
        half4 h;
        h.x = (_Float16)v.x; h.y = (_Float16)v.y;
        h.z = (_Float16)v.z; h.w = (_Float16)v.w;
        vh4[(size_t)(cbase + c_loc)*128 + rem] = h;
        float ra = s_acts[c_loc];
        s1[0] += ra*v.x; s2[0] = fmaf(ra*v.x, v.x, s2[0]);
        s1[1] += ra*v.y; s2[1] = fmaf(ra*v.y, v.y, s2[1]);
        s1[2] += ra*v.z; s2[2] = fmaf(ra*v.z, v.z, s2[2]);
        s1[3] += ra*v.w; s2[3] = fmaf(ra*v.w, v.w, s2[3]);
        sumR += ra;
    }
    if (child_sub) {
        r1[rem] = make_float4(s1[0], s1[1], s1[2], s1[3]);
        r2[rem] = make_float4(s2[0], s2[1], s2[2], s2[3]);
        if (rem == 0) sR1 = sumR;
    }
    __syncthreads();
    if (!child_sub) {
        float4 o1 = r1[rem], o2 = r2[rem];
        ((float4*)(ws + PA_S1))[bid*128 + rem] =
            make_float4(s1[0]+o1.x, s1[1]+o1.y, s1[2]+o1.z, s1[3]+o1.w);
        ((float4*)(ws + PA_S2))[bid*128 + rem] =
            make_float4(s2[0]+o2.x, s2[1]+o2.y, s2[2]+o2.z, s2[3]+o2.w);
        if (rem == 0) ws[PA_SR + bid] = sumR + sR1;
    }
}

// ---------------- Kernel B: fused finalize (mu/sig/L in LDS) + lognum ------
// grid = NBLK, block = 256. Each block redundantly reduces its bhw's CH chunk
// slots (L2-hot; R5 proved splitting this out is a net loss), then runs the
// lognum pass over its own chunk from the fp16 shadow votes.
__global__ __launch_bounds__(256) void kB(const float* __restrict__ beta_a,
        const float* __restrict__ beta_u, float* __restrict__ ws) {
    __shared__ float s_mu[512], s_w[512], s_L[32], smax[4];
    const int bid = blockIdx.x;
    const int bhw = bid >> 2;
    const int cbase = (bid & 3) * CPC;
    const int t = threadIdx.x;
    float sumR = 0.f;
    #pragma unroll
    for (int ch = 0; ch < CH; ++ch) sumR += ws[PA_SR + bhw*CH + ch];
    #pragma unroll
    for (int half = 0; half < 2; ++half) {
        const int idx = t + half*256;       // = o*16 + a
        float s1 = 0.f, s2 = 0.f;
        #pragma unroll
        for (int ch = 0; ch < CH; ++ch) {
            s1 += ws[PA_S1 + (size_t)(bhw*CH + ch)*512 + idx];
            s2 += ws[PA_S2 + (size_t)(bhw*CH + ch)*512 + idx];
        }
        const int o = idx >> 4, a = idx & 15;
        float mu  = s1 / (sumR + EPSF);
        float sig = (s2 - mu*(2.f*s1 - mu*sumR)) / (sumR + EPSF) + MINVAR;
        s_mu[a*32 + o] = mu;
        s_w [a*32 + o] = 0.5f / sig;
        float cost = (beta_u[o] - 0.5f*logf(sig + EPSF)) * sumR;
        float ps   = logf(6.2831853071795864f * sig);
        #pragma unroll
        for (int d = 1; d < 16; d <<= 1) {
            cost += __shfl_xor(cost, d);
            ps   += __shfl_xor(ps, d);
        }
        if (a == 0) {
            float aj = 1.0f/(1.0f + expf(-TEMP0*(beta_a[o] - cost)));
            s_L[o] = logf(aj) - ps;
        }
    }
    __syncthreads();
    const int child_sub = t >> 7;
    const int rem = t & 127;
    const int o = rem >> 2;
    const int quad = rem & 3;
    float mur[4], wr[4];
    #pragma unroll
    for (int j = 0; j < 4; ++j) {
        mur[j] = s_mu[(quad*4 + j)*32 + o];
        wr[j]  = s_w [(quad*4 + j)*32 + o];
    }
    const float L = s_L[o];
    const half4* vh4 = (const half4*)(ws + VH_OFF) + (size_t)bhw*(VPB/4);
    float* lp = ws + LOGNUM_OFF + (size_t)bhw*(NC*NO);
    float tmax = -3.0e38f;
    #pragma unroll 6
    for (int it = 0; it < ITERS; ++it) {
        const int c = cbase + it*2 + child_sub;
        half4 hv = vh4[(size_t)c*128 + rem];
        float d0 = (float)hv.x - mur[0];
        float acc = d0*d0*wr[0];
        float d1 = (float)hv.y - mur[1]; acc = fmaf(d1*d1, wr[1], acc);
        float d2 = (float)hv.z - mur[2]; acc = fmaf(d2*d2, wr[2], acc);
        float d3 = (float)hv.w - mur[3]; acc = fmaf(d3*d3, wr[3], acc);
        acc += __shfl_xor(acc, 1);
        acc += __shfl_xor(acc, 2);          // all quads hold the full a-sum
        float ln = L - acc;
        if (quad == 0) lp[c*32 + o] = ln;
        tmax = fmaxf(tmax, ln);
    }
    #pragma unroll
    for (int d = 1; d < 64; d <<= 1) tmax = fmaxf(tmax, __shfl_xor(tmax, d));
    if ((t & 63) == 0) smax[t >> 6] = tmax;
    __syncthreads();
    if (t == 0)
        ws[BM_OFF + bid] = fmaxf(fmaxf(smax[0], smax[1]), fmaxf(smax[2], smax[3]));
}

// ---------------- Kernel C: inline global max + sum_o ap, scatter ----------
// grid = NBHW*4, block = 256; t -> (c_loc = t>>5, o = t&31)
__global__ __launch_bounds__(256) void kC(float* __restrict__ ws) {
    __shared__ float smax[4];
    const int bid = blockIdx.x;
    const int bhw = bid >> 2;
    const int cbase = (bid & 3) * CPC;
    const int t = threadIdx.x;
    float m = -3.0e38f;
    for (int i = t; i < NBLK; i += 256) m = fmaxf(m, ws[BM_OFF + i]);
    #pragma unroll
    for (int d = 1; d < 64; d <<= 1) m = fmaxf(m, __shfl_xor(m, d));
    if ((t & 63) == 0) smax[t >> 6] = m;
    __syncthreads();
    const float M = fmaxf(fmaxf(smax[0], smax[1]), fmaxf(smax[2], smax[3]));
    const int b = bhw / (NH*NW);
    const int rem = bhw % (NH*NW);
    const int y = rem / NW, x = rem % NW;
    const float* lp = ws + LOGNUM_OFF + (size_t)bhw*(NC*NO);
    float* dense = ws + DENSE_OFF;
    const int o = t & 31;
    for (int it = 0; it < CPC/8; ++it) {
        const int c = cbase + it*8 + (t >> 5);
        float s = expf(lp[c*32 + o] - M);
        #pragma unroll
        for (int d = 1; d < 32; d <<= 1) s += __shfl_xor(s, d);
        if (o == 0) {
            const int i = c & 31, kk = c >> 5;
            const int ky = kk / 3, kx = kk % 3;
            atomicAdd(&dense[((b*HR + y+ky)*WR + (x+kx))*NI + i], s);
        }
    }
}

// ---------------- Kernel D: final m_step partial moments -------------------
// grid = NBLK, block = 256. Inline global max; ra staged in LDS; reads the
// fp16 shadow votes (half the requests of the fp32 stream).
__global__ __launch_bounds__(256) void kD(const float* __restrict__ acts,
        float* __restrict__ ws) {
    __shared__ float s_rd[CPC];
    __shared__ float s_ra[CPC*NO];
    __shared__ float smax[4];
    __shared__ float4 r1[128], r2[128];
    __shared__ float sSR[64];
    const int bid = blockIdx.x;
    const int bhw = bid >> 2;
    const int cbase = (bid & 3) * CPC;
    const int t = threadIdx.x;
    const int b = bhw / (NH*NW);
    const int remhw = bhw % (NH*NW);
    const int y = remhw / NW, x = remhw % NW;
    float m = -3.0e38f;
    for (int i = t; i < NBLK; i += 256) m = fmaxf(m, ws[BM_OFF + i]);
    #pragma unroll
    for (int d = 1; d < 64; d <<= 1) m = fmaxf(m, __shfl_xor(m, d));
    if ((t & 63) == 0) smax[t >> 6] = m;
    if (t < CPC) {
        const int c = cbase + t;
        const int i = c & 31, kk = c >> 5;
        const int ky = kk / 3, kx = kk % 3;
        float dn = ws[DENSE_OFF + ((b*HR + y+ky)*WR + (x+kx))*NI + i];
        s_rd[t] = acts[bhw*NC + c] / (dn + EPSF);
    }
    __syncthreads();
    const float M = fmaxf(fmaxf(smax[0], smax[1]), fmaxf(smax[2], smax[3]));
    const float* lp = ws + LOGNUM_OFF + (size_t)bhw*(NC*NO) + (size_t)cbase*32;
    for (int idx = t; idx < CPC*NO; idx += 256)
        s_ra[idx] = s_rd[idx >> 5] * expf(lp[idx] - M);
    __syncthreads();
    const int child_sub = t >> 7;
    const int rem = t & 127;
    const int o = rem >> 2;
    const int quad = rem & 3;
    const half4* vh4 = (const half4*)(ws + VH_OFF) + (size_t)bhw*(VPB/4);
    float s1[4] = {0,0,0,0}, s2[4] = {0,0,0,0};
    float sumR = 0.f;
    #pragma unroll 6
    for (int it = 0; it < ITERS; ++it) {
        const int c_loc = it*2 + child_sub;
        half4 hv = vh4[(size_t)(cbase + c_loc)*128 + rem];
        float vx = (float)hv.x, vy = (float)hv.y, vz = (float)hv.z, vw = (float)hv.w;
        float ra = s_ra[c_loc*32 + o];          // 4-lane broadcast
        s1[0] += ra*vx; s2[0] = fmaf(ra*vx, vx, s2[0]);
        s1[1] += ra*vy; s2[1] = fmaf(ra*vy, vy, s2[1]);
        s1[2] += ra*vz; s2[2] = fmaf(ra*vz, vz, s2[2]);
        s1[3] += ra*vw; s2[3] = fmaf(ra*vw, vw, s2[3]);
        sumR += ra;
    }
    // per-(child_sub, o) partial: quads are identical, take quad 0's only
    if (quad == 0) sSR[child_sub*32 + o] = sumR;
    if (child_sub) {
        r1[rem] = make_float4(s1[0], s1[1], s1[2], s1[3]);
        r2[rem] = make_float4(s2[0], s2[1], s2[2], s2[3]);
    }
    __syncthreads();
    if (!child_sub) {
        float4 o1 = r1[rem], o2 = r2[rem];
        ((float4*)(ws + PD_S1))[bid*128 + rem] =
            make_float4(s1[0]+o1.x, s1[1]+o1.y, s1[2]+o1.z, s1[3]+o1.w);
        ((float4*)(ws + PD_S2))[bid*128 + rem] =
            make_float4(s2[0]+o2.x, s2[1]+o2.y, s2[2]+o2.z, s2[3]+o2.w);
    }
    if (t < 32) ws[PD_SR + bid*32 + t] = sSR[t] + sSR[32 + t];
}

// ---------------- Kernel D2: reduce chunk slots, write outputs -------------
// grid = NBHW*2, block = 256, t = (o_loc<<4)|a
__global__ __launch_bounds__(256) void kD2(const float* __restrict__ beta_a,
        const float* __restrict__ beta_u, const float* __restrict__ ws,
        float* __restrict__ out) {
    const int bid = blockIdx.x;
    const int bhw = bid >> 1;
    const int obase = (bid & 1) * 16;
    const int t = threadIdx.x;
    const int a = t & 15;
    const int o = obase + (t >> 4);
    float s1 = 0.f, s2 = 0.f, sumR = 0.f;
    #pragma unroll
    for (int ch = 0; ch < CH; ++ch) {
        s1   += ws[PD_S1 + (size_t)(bhw*CH + ch)*512 + obase*16 + t];
        s2   += ws[PD_S2 + (size_t)(bhw*CH + ch)*512 + obase*16 + t];
        sumR += ws[PD_SR + (bhw*CH + ch)*32 + o];
    }
    float mu  = s1 / (sumR + EPSF);
    float sig = (s2 - mu*(2.f*s1 - mu*sumR)) / (sumR + EPSF) + MINVAR;
    out[bhw*512 + obase*16 + t] = mu;            // poses (b,h,w,o,a,a)
    float cost = (beta_u[o] - 0.5f*logf(sig + EPSF)) * sumR;
    #pragma unroll
    for (int d = 1; d < 16; d <<= 1) cost += __shfl_xor(cost, d);
    if (a == 0) {
        float aj = 1.0f/(1.0f + expf(-TEMPF*(beta_a[o] - cost)));
        out[NBHW*512 + bhw*32 + o] = aj;         // acts (b,h,w,o)
    }
}

extern "C" void kernel_launch(void* const* d_in, const int* in_sizes, int n_in,
                              void* d_out, int out_size, void* d_ws, size_t ws_size,
                              hipStream_t stream) {
    const float* votes  = (const float*)d_in[0];
    const float* acts   = (const float*)d_in[1];
    const float* beta_a = (const float*)d_in[2];
    const float* beta_u = (const float*)d_in[3];
    float* ws  = (float*)d_ws;
    float* out = (float*)d_out;

    kA <<<NBLK,   256, 0, stream>>>(votes, acts, ws);
    kB <<<NBLK,   256, 0, stream>>>(beta_a, beta_u, ws);
    kC <<<NBHW*4, 256, 0, stream>>>(ws);
    kD <<<NBLK,   256, 0, stream>>>(acts, ws);
    kD2<<<NBHW*2, 256, 0, stream>>>(beta_a, beta_u, ws, out);
}

// Round 8
// 285.856 us; speedup vs baseline: 1.4020x; 1.1065x over previous
//
#include <hip/hip_runtime.h>
#include <math.h>

// Problem constants (fixed by setup_inputs)
#define NB 2
#define NH 12
#define NW 12
#define NK 3
#define NI 32
#define NO 32
#define NBHW (NB*NH*NW)       // 288 spatial positions
#define NC (NK*NK*NI)         // 288 children per position
#define VPB (NC*NO*16)        // 147456 votes floats per bhw (c-major, then o, then a)
#define HR 14
#define WR 14
#define EPSF 1e-7f
#define MINVAR 5e-4f
#define TEMP0 0.0005f         // 0.01*(1-0.95^1), m_step it=0
#define TEMPF 0.00142625f     // 0.01*(1-0.95^3), final m_step

// R7 proved pass time is invariant to bytes/lines/occupancy/ILP -> the only
// remaining lever is PASS COUNT. Fuse moments+lognum (one votes read) and
// final-moments+output (one votes read): 3 votes passes -> 2.
// Block = one (bhw, o-pair) slice: 288 children x 32 elems = 36 KB in LDS.
#define OGRP 16               // o-pairs per bhw
#define GF (NBHW*OGRP)        // 4608 blocks for the two fused votes kernels
#define LDSROW 289            // +1 pad: element-major rows, bank-conflict-free

// ---- Workspace layout (float offsets) ----
#define DENSE_N (NB*HR*WR*NI) // 12544
#define DENSE_OFF 0
#define BM_OFF  (DENSE_OFF + DENSE_N)   // [GF] per-block lognum max
#define M_OFF   (BM_OFF + GF)           // [4] global lognum max (kC publishes)
#define LP_OFF  (M_OFF + 4)             // lognum TRANSPOSED: [bhw][o][c]

// ================= kF1: fused m_step-1 moments + lognum (1 votes read) =====
// grid = GF, block = 256. Block owns (bhw, o0=2*og): loads votes slice
// [c=0..287][o0*16 .. o0*16+32) into LDS element-major, reduces moments,
// computes mu/sig/L in-block, emits lognum rows [o0][c], [o0+1][c].
__global__ __launch_bounds__(256) void kF1(const float* __restrict__ votes,
        const float* __restrict__ acts, const float* __restrict__ beta_a,
        const float* __restrict__ beta_u, float* __restrict__ ws) {
    __shared__ float lds_v[32][LDSROW];
    __shared__ float s_acts[NC];
    __shared__ float red[3][8][32];
    __shared__ float s_mu[32], s_w[32], s_L[2], smax[4];
    const int bid = blockIdx.x;
    const int bhw = bid >> 4;
    const int o0 = (bid & 15) * 2;
    const int t = threadIdx.x;
    // fold dense-grid zeroing into the first kernel (4608*3 >= 12544)
    #pragma unroll
    for (int j = 0; j < 3; ++j) {
        const int idx = bid*3 + j;
        if (idx < DENSE_N) ws[DENSE_OFF + idx] = 0.f;
    }
    s_acts[t] = acts[bhw*NC + t] * (1.0f/NO);
    if (t < 32) s_acts[256 + t] = acts[bhw*NC + 256 + t] * (1.0f/NO);
    // stage 1: votes slice -> LDS (element-major, padded rows)
    const float4* vb4 = (const float4*)votes + (size_t)bhw*(VPB/4) + o0*4;
    {
        const int f = t & 7;          // float4 within the 32-elem slice
        const int cof = t >> 3;       // child within group of 32
        #pragma unroll
        for (int cb = 0; cb < 9; ++cb) {
            const int c = cb*32 + cof;
            float4 v = vb4[(size_t)c*128 + f];
            lds_v[f*4+0][c] = v.x;
            lds_v[f*4+1][c] = v.y;
            lds_v[f*4+2][c] = v.z;
            lds_v[f*4+3][c] = v.w;
        }
    }
    __syncthreads();
    // stage 2: moments (reduce over 288 children, 8 c_subs x 32 elems)
    {
        const int c_sub = t >> 5, e = t & 31;
        float s1 = 0.f, s2 = 0.f, sR = 0.f;
        #pragma unroll 6
        for (int k = 0; k < 36; ++k) {
            const int c = k*8 + c_sub;
            float v = lds_v[e][c];
            float ra = s_acts[c];
            s1 += ra*v; s2 = fmaf(ra*v, v, s2); sR += ra;
        }
        red[0][c_sub][e] = s1; red[1][c_sub][e] = s2; red[2][c_sub][e] = sR;
    }
    __syncthreads();
    if (t < 32) {
        const int e = t;
        float s1 = 0.f, s2 = 0.f, sR = 0.f;
        #pragma unroll
        for (int cs = 0; cs < 8; ++cs) {
            s1 += red[0][cs][e]; s2 += red[1][cs][e]; sR += red[2][cs][e];
        }
        const int o = o0 + (e >> 4);
        float mu  = s1 / (sR + EPSF);
        float sig = (s2 - mu*(2.f*s1 - mu*sR)) / (sR + EPSF) + MINVAR;
        s_mu[e] = mu;
        s_w[e]  = 0.5f / sig;
        float cost = (beta_u[o] - 0.5f*logf(sig + EPSF)) * sR;
        float ps   = logf(6.2831853071795864f * sig);
        #pragma unroll
        for (int d = 1; d < 16; d <<= 1) {   // 16-lane (per-o) reduce
            cost += __shfl_xor(cost, d);
            ps   += __shfl_xor(ps, d);
        }
        if ((e & 15) == 0) {
            float aj = 1.0f/(1.0f + expf(-TEMP0*(beta_a[o] - cost)));
            s_L[e >> 4] = logf(aj) - ps;
        }
    }
    __syncthreads();
    // stage 3: lognum from LDS; write TRANSPOSED rows (coalesced)
    float* lpt = ws + LP_OFF + (size_t)bhw*(NC*NO) + (size_t)o0*NC;
    float tmax = -3.0e38f;
    #pragma unroll
    for (int pass = 0; pass < 2; ++pass) {
        const int c = pass*256 + t;
        if (c < NC) {
            float acc0 = 0.f, acc1 = 0.f;
            #pragma unroll
            for (int e = 0; e < 16; ++e) {
                float d0 = lds_v[e][c]    - s_mu[e];
                acc0 = fmaf(d0*d0, s_w[e], acc0);
                float d1 = lds_v[e+16][c] - s_mu[e+16];
                acc1 = fmaf(d1*d1, s_w[e+16], acc1);
            }
            float ln0 = s_L[0] - acc0, ln1 = s_L[1] - acc1;
            lpt[c] = ln0; lpt[NC + c] = ln1;
            tmax = fmaxf(tmax, fmaxf(ln0, ln1));
        }
    }
    #pragma unroll
    for (int d = 1; d < 64; d <<= 1) tmax = fmaxf(tmax, __shfl_xor(tmax, d));
    if ((t & 63) == 0) smax[t >> 6] = tmax;
    __syncthreads();
    if (t == 0)
        ws[BM_OFF + bid] = fmaxf(fmaxf(smax[0], smax[1]), fmaxf(smax[2], smax[3]));
}

// ================= kC: global max + denominator scatter =====================
// grid = NBHW, block = 256. Per c: sum exp over o (coalesced row reads of the
// transposed lognum), one atomicAdd per c. Publishes M for kF3.
__global__ __launch_bounds__(256) void kC(float* __restrict__ ws) {
    __shared__ float smax[4];
    const int bhw = blockIdx.x;
    const int t = threadIdx.x;
    float m = -3.0e38f;
    for (int i = t; i < GF; i += 256) m = fmaxf(m, ws[BM_OFF + i]);
    #pragma unroll
    for (int d = 1; d < 64; d <<= 1) m = fmaxf(m, __shfl_xor(m, d));
    if ((t & 63) == 0) smax[t >> 6] = m;
    __syncthreads();
    const float M = fmaxf(fmaxf(smax[0], smax[1]), fmaxf(smax[2], smax[3]));
    if (bhw == 0 && t == 0) ws[M_OFF] = M;   // kernel boundary -> visible to kF3
    const int b = bhw / (NH*NW);
    const int rem = bhw % (NH*NW);
    const int y = rem / NW, x = rem % NW;
    const float* lpt = ws + LP_OFF + (size_t)bhw*(NC*NO);
    float* dense = ws + DENSE_OFF;
    #pragma unroll
    for (int pass = 0; pass < 2; ++pass) {
        const int c = pass*256 + t;
        if (c < NC) {
            float s = 0.f;
            for (int o = 0; o < NO; ++o) s += expf(lpt[(size_t)o*NC + c] - M);
            const int i = c & 31, kk = c >> 5;
            const int ky = kk / 3, kx = kk % 3;
            atomicAdd(&dense[((b*HR + y+ky)*WR + (x+kx))*NI + i], s);
        }
    }
}

// ================= kF3: fused final moments + output (1 votes read) ========
// grid = GF, block = 256. Same slice geometry as kF1; ra[o][c] staged from
// transposed lognum + dense gather; writes poses/acts directly (no kD2).
__global__ __launch_bounds__(256) void kF3(const float* __restrict__ votes,
        const float* __restrict__ acts, const float* __restrict__ beta_a,
        const float* __restrict__ beta_u, float* __restrict__ ws,
        float* __restrict__ out) {
    __shared__ float lds_v[32][LDSROW];
    __shared__ float s_ra[2][NC];
    __shared__ float red[3][8][32];
    const int bid = blockIdx.x;
    const int bhw = bid >> 4;
    const int o0 = (bid & 15) * 2;
    const int t = threadIdx.x;
    const int b = bhw / (NH*NW);
    const int remhw = bhw % (NH*NW);
    const int y = remhw / NW, x = remhw % NW;
    const float M = ws[M_OFF];
    const float* lpt = ws + LP_OFF + (size_t)bhw*(NC*NO) + (size_t)o0*NC;
    #pragma unroll
    for (int pass = 0; pass < 2; ++pass) {
        const int c = pass*256 + t;
        if (c < NC) {
            const int i = c & 31, kk = c >> 5;
            const int ky = kk / 3, kx = kk % 3;
            float dn = ws[DENSE_OFF + ((b*HR + y+ky)*WR + (x+kx))*NI + i];
            float r = acts[bhw*NC + c] / (dn + EPSF);
            s_ra[0][c] = r * expf(lpt[c] - M);
            s_ra[1][c] = r * expf(lpt[NC + c] - M);
        }
    }
    // votes slice -> LDS (same pattern as kF1)
    const float4* vb4 = (const float4*)votes + (size_t)bhw*(VPB/4) + o0*4;
    {
        const int f = t & 7;
        const int cof = t >> 3;
        #pragma unroll
        for (int cb = 0; cb < 9; ++cb) {
            const int c = cb*32 + cof;
            float4 v = vb4[(size_t)c*128 + f];
            lds_v[f*4+0][c] = v.x;
            lds_v[f*4+1][c] = v.y;
            lds_v[f*4+2][c] = v.z;
            lds_v[f*4+3][c] = v.w;
        }
    }
    __syncthreads();
    {
        const int c_sub = t >> 5, e = t & 31;
        const int o_sub = e >> 4;
        float s1 = 0.f, s2 = 0.f, sR = 0.f;
        #pragma unroll 6
        for (int k = 0; k < 36; ++k) {
            const int c = k*8 + c_sub;
            float v = lds_v[e][c];
            float ra = s_ra[o_sub][c];       // per-o weights (4-group broadcast)
            s1 += ra*v; s2 = fmaf(ra*v, v, s2); sR += ra;
        }
        red[0][c_sub][e] = s1; red[1][c_sub][e] = s2; red[2][c_sub][e] = sR;
    }
    __syncthreads();
    if (t < 32) {
        const int e = t;
        float s1 = 0.f, s2 = 0.f, sR = 0.f;
        #pragma unroll
        for (int cs = 0; cs < 8; ++cs) {
            s1 += red[0][cs][e]; s2 += red[1][cs][e]; sR += red[2][cs][e];
        }
        const int o = o0 + (e >> 4);
        float mu  = s1 / (sR + EPSF);     // sR is per-o (ra is o-dependent)
        float sig = (s2 - mu*(2.f*s1 - mu*sR)) / (sR + EPSF) + MINVAR;
        out[bhw*512 + o0*16 + e] = mu;    // poses (b,h,w,o,a,a)
        float cost = (beta_u[o] - 0.5f*logf(sig + EPSF)) * sR;
        #pragma unroll
        for (int d = 1; d < 16; d <<= 1) cost += __shfl_xor(cost, d);
        if ((e & 15) == 0) {
            float aj = 1.0f/(1.0f + expf(-TEMPF*(beta_a[o] - cost)));
            out[NBHW*512 + bhw*32 + o] = aj;   // acts (b,h,w,o)
        }
    }
}

extern "C" void kernel_launch(void* const* d_in, const int* in_sizes, int n_in,
                              void* d_out, int out_size, void* d_ws, size_t ws_size,
                              hipStream_t stream) {
    const float* votes  = (const float*)d_in[0];
    const float* acts   = (const float*)d_in[1];
    const float* beta_a = (const float*)d_in[2];
    const float* beta_u = (const float*)d_in[3];
    float* ws  = (float*)d_ws;
    float* out = (float*)d_out;

    kF1<<<GF,   256, 0, stream>>>(votes, acts, beta_a, beta_u, ws);
    kC <<<NBHW, 256, 0, stream>>>(ws);
    kF3<<<GF,   256, 0, stream>>>(votes, acts, beta_a, beta_u, ws, out);
}